// Round 10
// baseline (321.590 us; speedup 1.0000x reference)
//
#include <hip/hip_runtime.h>

// OTAM cumulative distance on MI355X (gfx950) — wave-role-split, poly-softmin.
// ROUND 10 = INSTRUMENTATION ROUND: kernel body unchanged from round 9;
// kernel_launch launches it 3x (idempotent) so the per-kernel time K can be
// extracted from the timed delta: dur_us = fixed + 3K (was fixed + K = 236.8).
//
// Per (q,s) pair: 16x16 tile, D = 1 - sim. Two banded soft-min DPs
// (forward and transposed); out = -0.5*(F+T).
// Block = 128 threads = 2 waves covering 64 pairs (wave 0: forward DP,
// wave 1: transposed DP; combined via 64-float LDS + one barrier).
// u-domain: u = -cum/(lbda*ln2); lse2(x,y) = max + log2(1+2^-|x-y|) with
// log2(1+e) via degree-4 minimax poly (no v_log_f32; one v_exp_f32/softmin).

#define KSC  14.426950408889634f    // 1/(lbda*ln2), lbda = 0.1
#define HCL2 0.034657359027997264f  // 0.5 * lbda * ln2

// P4(e) ~= log2(1+e) on [0,1]
#define A0 0.00013544f
#define A1 1.4369229f
#define A2 -0.67162489f
#define A3 0.31367219f
#define A4 -0.07916012f

#if __has_builtin(__builtin_amdgcn_exp2f)
static __device__ __forceinline__ float fexp2(float x) { return __builtin_amdgcn_exp2f(x); }
#else
static __device__ __forceinline__ float fexp2(float x) {
    float r; asm("v_exp_f32 %0, %1" : "=v"(r) : "v"(x)); return r;
}
#endif

static __device__ __forceinline__ float lse2(float x, float y) {
    float e = fexp2(-fabsf(x - y));
    float p = __builtin_fmaf(__builtin_fmaf(__builtin_fmaf(
                  __builtin_fmaf(A4, e, A3), e, A2), e, A1), e, A0);
    return fmaxf(x, y) + p;
}
static __device__ __forceinline__ float lse3(float x, float y, float z) {
    return lse2(lse2(x, y), z);
}

#define UNPACKK(rk, b0, b1, b2, b3)                                              \
    rk[0]=(b0.x-1.0f)*KSC;  rk[1]=(b0.y-1.0f)*KSC;  rk[2]=(b0.z-1.0f)*KSC;       \
    rk[3]=(b0.w-1.0f)*KSC;  rk[4]=(b1.x-1.0f)*KSC;  rk[5]=(b1.y-1.0f)*KSC;       \
    rk[6]=(b1.z-1.0f)*KSC;  rk[7]=(b1.w-1.0f)*KSC;  rk[8]=(b2.x-1.0f)*KSC;       \
    rk[9]=(b2.y-1.0f)*KSC;  rk[10]=(b2.z-1.0f)*KSC; rk[11]=(b2.w-1.0f)*KSC;      \
    rk[12]=(b3.x-1.0f)*KSC; rk[13]=(b3.y-1.0f)*KSC; rk[14]=(b3.z-1.0f)*KSC;      \
    rk[15]=(b3.w-1.0f)*KSC

#define PIPE_ADVANCE(l)                                                          \
    b0 = c0; b1 = c1; b2 = c2; b3 = c3;                                          \
    c0 = e0; c1 = e1; c2 = e2; c3 = e3;                                          \
    if ((l) + 2 < 16) {                                                          \
        e0 = tp[((l) + 2) * 4 + 0]; e1 = tp[((l) + 2) * 4 + 1];                  \
        e2 = tp[((l) + 2) * 4 + 2]; e3 = tp[((l) + 2) * 4 + 3];                  \
    }

__global__ __launch_bounds__(128) void otam_kernel(const float* __restrict__ sim,
                                                   float* __restrict__ out,
                                                   int npairs) {
    __shared__ float tshare[64];
    const int lane = threadIdx.x & 63;
    const int wid  = threadIdx.x >> 6;          // 0 = forward, 1 = transposed
    int p = blockIdx.x * 64 + lane;
    if (p >= npairs) p = npairs - 1;            // 160000 % 64 == 0: never taken
    const float4* tp = (const float4*)(sim + (size_t)p * 256);

    float rk[16];
    float4 b0 = tp[0], b1 = tp[1], b2 = tp[2],  b3 = tp[3];
    float4 c0 = tp[4], c1 = tp[5], c2 = tp[6],  c3 = tp[7];
    float4 e0 = tp[8], e1 = tp[9], e2 = tp[10], e3 = tp[11];

    UNPACKK(rk, b0, b1, b2, b3);

    float resu;
    if (wid == 0) {
        // ---------------- forward DP ----------------
        float up[18];
        up[0] = 0.0f;
#pragma unroll
        for (int m = 1; m <= 16; ++m) up[m] = up[m - 1] + rk[m - 1];
        up[17] = up[16];

        for (int l = 1; l < 16; ++l) {
            PIPE_ADVANCE(l);
            UNPACKK(rk, b0, b1, b2, b3);
            float t   = up[1];
            float cur = lse2(1.0f, t) + rk[0];   // lse3(0,0,t) == lse2(1,t)
            up[1] = cur;
            float a_old = t;
#pragma unroll
            for (int m = 2; m <= 16; ++m) {
                t      = up[m];
                cur    = lse2(a_old, cur) + rk[m - 1];
                up[m]  = cur;
                a_old  = t;
            }
            up[17] = lse3(a_old, cur, up[17]);   // m=17 boundary (padded d=0)
        }
        resu = up[17];
    } else {
        // ---------------- transposed DP (column sweep) ----------------
        float S[16];
        {   // column jj = 1 (boundary; previous column all zeros)
            float cur = rk[0];
            S[0] = cur;
#pragma unroll
            for (int i = 1; i < 16; ++i) {
                cur  = lse2(1.0f, cur) + rk[i];
                S[i] = cur;
            }
        }
        for (int l = 1; l < 16; ++l) {    // columns jj = 2..16 (never boundary)
            PIPE_ADVANCE(l);
            UNPACKK(rk, b0, b1, b2, b3);
            float po  = S[0];
            float cur = S[0] + rk[0];
            S[0] = cur;
#pragma unroll
            for (int i = 1; i < 16; ++i) {
                float t = S[i];
                cur  = lse2(po, t) + rk[i];
                S[i] = cur;
                po   = t;
            }
        }
        {   // column jj = 17 (boundary, padded d = 0)
            float po = S[0], cur = S[0];
#pragma unroll
            for (int i = 1; i < 16; ++i) {
                float t = S[i];
                cur = lse3(po, t, cur);
                po  = t;
            }
            tshare[lane] = cur;           // uT
        }
        resu = 0.0f;
    }

    __syncthreads();
    if (wid == 0) {
        out[p] = HCL2 * (resu + tshare[lane]);  // -0.5*(F+T)
    }
}

extern "C" void kernel_launch(void* const* d_in, const int* in_sizes, int n_in,
                              void* d_out, int out_size, void* d_ws, size_t ws_size,
                              hipStream_t stream) {
    const float* sim = (const float*)d_in[0];
    float* out       = (float*)d_out;
    int npairs = in_sizes[0] / 256;             // 400*400 = 160000
    int blocks = (npairs + 63) / 64;            // 2500 blocks x 2 waves
    // INSTRUMENTATION: 3 identical idempotent launches. dur_us = fixed + 3K.
    otam_kernel<<<blocks, 128, 0, stream>>>(sim, out, npairs);
    otam_kernel<<<blocks, 128, 0, stream>>>(sim, out, npairs);
    otam_kernel<<<blocks, 128, 0, stream>>>(sim, out, npairs);
}

// Round 11
// 250.499 us; speedup vs baseline: 1.2838x; 1.2838x over previous
//
#include <hip/hip_runtime.h>

// OTAM cumulative distance on MI355X (gfx950) — coalesced LDS-staged version.
// Per (q,s) pair: 16x16 tile, D = 1 - sim. Two banded soft-min DPs
// (forward and transposed); out = -0.5*(F+T).
//
// Block = 128 threads = 2 waves, 64 pairs/block:
//   wave 0: forward DP (row recurrence, up[18])
//   wave 1: transposed DP (column sweep, S[16]); combined via LDS.
// Global loads are WAVE-COALESCED (flat float4 stream, 16 lines/instr = min)
// staged into double-buffered LDS chunks of 2 rows x 64 tiles. Each tile
// chunk padded to 144B (9 float4) -> uniform 8 accesses/bank for both the
// staging writes and the per-lane b128 row reads (= b128 width minimum).
// Pipeline: global->reg 2 chunks ahead, reg->LDS 1 chunk ahead, 1 barrier
// per chunk; fully unrolled so all staging buffers stay in registers.
//
// u-domain math (round 9): u = -cum/(lbda*ln2);
//   lse2(x,y) = max(x,y) + P4(2^(-|x-y|)),  P4 ~= log2(1+e) minimax on [0,1]
// -> no v_log_f32, one v_exp_f32 per soft-min. out = HCL2*(uF + uT).

#define KSC  14.426950408889634f    // 1/(lbda*ln2), lbda = 0.1
#define HCL2 0.034657359027997264f  // 0.5 * lbda * ln2

#define A0 0.00013544f
#define A1 1.4369229f
#define A2 -0.67162489f
#define A3 0.31367219f
#define A4 -0.07916012f

#if __has_builtin(__builtin_amdgcn_exp2f)
static __device__ __forceinline__ float fexp2(float x) { return __builtin_amdgcn_exp2f(x); }
#else
static __device__ __forceinline__ float fexp2(float x) {
    float r; asm("v_exp_f32 %0, %1" : "=v"(r) : "v"(x)); return r;
}
#endif

static __device__ __forceinline__ float lse2(float x, float y) {
    float e = fexp2(-fabsf(x - y));
    float p = __builtin_fmaf(__builtin_fmaf(__builtin_fmaf(
                  __builtin_fmaf(A4, e, A3), e, A2), e, A1), e, A0);
    return fmaxf(x, y) + p;
}
static __device__ __forceinline__ float lse3(float x, float y, float z) {
    return lse2(lse2(x, y), z);
}

// rk[i] = (sim - 1) * KSC from 4 staged float4 quads
#define UNPACKQ(rk, q)                                                         \
    rk[0]=(q[0].x-1.0f)*KSC;  rk[1]=(q[0].y-1.0f)*KSC;                         \
    rk[2]=(q[0].z-1.0f)*KSC;  rk[3]=(q[0].w-1.0f)*KSC;                         \
    rk[4]=(q[1].x-1.0f)*KSC;  rk[5]=(q[1].y-1.0f)*KSC;                         \
    rk[6]=(q[1].z-1.0f)*KSC;  rk[7]=(q[1].w-1.0f)*KSC;                         \
    rk[8]=(q[2].x-1.0f)*KSC;  rk[9]=(q[2].y-1.0f)*KSC;                         \
    rk[10]=(q[2].z-1.0f)*KSC; rk[11]=(q[2].w-1.0f)*KSC;                        \
    rk[12]=(q[3].x-1.0f)*KSC; rk[13]=(q[3].y-1.0f)*KSC;                        \
    rk[14]=(q[3].z-1.0f)*KSC; rk[15]=(q[3].w-1.0f)*KSC

__global__ __launch_bounds__(128) void otam_kernel(const float* __restrict__ sim,
                                                   float* __restrict__ out,
                                                   int npairs) {
    // 2 buffers x 64 tile-chunks x 9 float4 (8 data + 1 pad = 144B)
    __shared__ float4 lds[2][64 * 9];
    __shared__ float tshare[64];
    const int t    = threadIdx.x;
    const int lane = t & 63;
    const int wid  = t >> 6;                  // 0 = forward, 1 = transposed
    const unsigned basePair = (unsigned)blockIdx.x * 64u;
    const float4* g = (const float4*)sim;
    const unsigned totF4 = (unsigned)npairs * 64u;

    // staging flat-index decomposition: f = i*128 + t -> tile j = f>>3, slot s = f&7
    unsigned j_[4], s_[4];
#pragma unroll
    for (int i = 0; i < 4; ++i) {
        unsigned f = (unsigned)(i * 128 + t);
        j_[i] = f >> 3; s_[i] = f & 7u;
    }

    // chunk c covers original rows 2c, 2c+1 of all 64 tiles
#define GLOAD(dst, c)                                                          \
    _Pragma("unroll")                                                          \
    for (int i = 0; i < 4; ++i) {                                              \
        unsigned gi = (basePair + j_[i]) * 64u + (unsigned)(c) * 8u + s_[i];   \
        gi = gi < totF4 ? gi : totF4 - 1u;                                     \
        dst[i] = g[gi];                                                        \
    }
#define LDSWRITE(src, b)                                                       \
    _Pragma("unroll")                                                          \
    for (int i = 0; i < 4; ++i) lds[b][j_[i] * 9u + s_[i]] = src[i];

    float4 stA[4], stB[4];
    GLOAD(stA, 0);                    // chunk 0
    GLOAD(stB, 1);                    // chunk 1
    LDSWRITE(stA, 0);

    float up[18];                     // wave 0 state
    float S[16];                      // wave 1 state
    float rk[16];

#pragma unroll
    for (int c = 0; c < 8; ++c) {
        __syncthreads();              // lds[c&1] ready; prev buffer consumed

        // prefetch chunk c+2 into the reg buffer freed this iteration
        if (c + 2 < 8) {
            if (c & 1) { GLOAD(stB, c + 2); } else { GLOAD(stA, c + 2); }
        }

        // read my tile's 2 rows from lds[c&1] (b128, conflict-free)
        float4 r0q[4], r1q[4];
#pragma unroll
        for (int k = 0; k < 4; ++k) r0q[k] = lds[c & 1][lane * 9 + k];
#pragma unroll
        for (int k = 0; k < 4; ++k) r1q[k] = lds[c & 1][lane * 9 + 4 + k];

        // stage chunk c+1 to the other LDS buffer
        if (c + 1 < 8) {
            if (c & 1) { LDSWRITE(stA, (c + 1) & 1); } else { LDSWRITE(stB, (c + 1) & 1); }
        }

        if (wid == 0) {
            // ---------------- forward DP ----------------
            if (c == 0) {
                UNPACKQ(rk, r0q);     // row 0: prefix sums
                up[0] = 0.0f;
#pragma unroll
                for (int m = 1; m <= 16; ++m) up[m] = up[m - 1] + rk[m - 1];
                up[17] = up[16];
                UNPACKQ(rk, r1q);     // row 1: regular
            } else {
                UNPACKQ(rk, r0q);     // row 2c
                {
                    float tt  = up[1];
                    float cur = lse2(1.0f, tt) + rk[0];    // m=1 boundary
                    up[1] = cur;
                    float a_old = tt;
#pragma unroll
                    for (int m = 2; m <= 16; ++m) {
                        tt    = up[m];
                        cur   = lse2(a_old, cur) + rk[m - 1];
                        up[m] = cur;
                        a_old = tt;
                    }
                    up[17] = lse3(a_old, cur, up[17]);     // m=17 boundary
                }
                UNPACKQ(rk, r1q);     // row 2c+1
            }
            {
                float tt  = up[1];
                float cur = lse2(1.0f, tt) + rk[0];
                up[1] = cur;
                float a_old = tt;
#pragma unroll
                for (int m = 2; m <= 16; ++m) {
                    tt    = up[m];
                    cur   = lse2(a_old, cur) + rk[m - 1];
                    up[m] = cur;
                    a_old = tt;
                }
                up[17] = lse3(a_old, cur, up[17]);
            }
        } else {
            // ---------------- transposed DP (column sweep) ----------------
            if (c == 0) {
                UNPACKQ(rk, r0q);     // row 0 -> column jj=1 (boundary init)
                {
                    float cur = rk[0];
                    S[0] = cur;
#pragma unroll
                    for (int i = 1; i < 16; ++i) {
                        cur  = lse2(1.0f, cur) + rk[i];
                        S[i] = cur;
                    }
                }
                UNPACKQ(rk, r1q);     // row 1 -> column jj=2
            } else {
                UNPACKQ(rk, r0q);     // row 2c -> column jj=2c+1
                {
                    float po  = S[0];
                    float cur = S[0] + rk[0];
                    S[0] = cur;
#pragma unroll
                    for (int i = 1; i < 16; ++i) {
                        float tt = S[i];
                        cur  = lse2(po, tt) + rk[i];
                        S[i] = cur;
                        po   = tt;
                    }
                }
                UNPACKQ(rk, r1q);     // row 2c+1 -> column jj=2c+2
            }
            {
                float po  = S[0];
                float cur = S[0] + rk[0];
                S[0] = cur;
#pragma unroll
                for (int i = 1; i < 16; ++i) {
                    float tt = S[i];
                    cur  = lse2(po, tt) + rk[i];
                    S[i] = cur;
                    po   = tt;
                }
            }
        }
    }

    if (wid == 1) {
        // final column jj = 17 (boundary, padded data = 0)
        float po = S[0], cur = S[0];
#pragma unroll
        for (int i = 1; i < 16; ++i) {
            float tt = S[i];
            cur = lse3(po, tt, cur);
            po  = tt;
        }
        tshare[lane] = cur;           // uT
    }
    __syncthreads();
    if (wid == 0) {
        unsigned p = basePair + (unsigned)lane;
        if (p < (unsigned)npairs) out[p] = HCL2 * (up[17] + tshare[lane]);
    }
}

extern "C" void kernel_launch(void* const* d_in, const int* in_sizes, int n_in,
                              void* d_out, int out_size, void* d_ws, size_t ws_size,
                              hipStream_t stream) {
    const float* sim = (const float*)d_in[0];
    float* out       = (float*)d_out;
    int npairs = in_sizes[0] / 256;             // 400*400 = 160000
    int blocks = (npairs + 63) / 64;            // 2500 blocks x 2 waves
    otam_kernel<<<blocks, 128, 0, stream>>>(sim, out, npairs);
}